// Round 1
// 1027.956 us; speedup vs baseline: 1.0044x; 1.0044x over previous
//
#include <hip/hip_runtime.h>
#include <math.h>

typedef _Float16 h8 __attribute__((ext_vector_type(8)));
typedef _Float16 h4 __attribute__((ext_vector_type(4)));
typedef float    f4 __attribute__((ext_vector_type(4)));

#define NQ    1024
#define HWK   4096
#define DM    512
#define NH    8
#define DKH   64

// load 8 consecutive fp32 and convert to f16 vector (for MFMA operand)
__device__ inline h8 cvt_h8(const float* __restrict__ p) {
    const f4* q = (const f4*)p;
    f4 a = q[0], b = q[1];
    h8 r;
    r[0] = (_Float16)a[0]; r[1] = (_Float16)a[1];
    r[2] = (_Float16)a[2]; r[3] = (_Float16)a[3];
    r[4] = (_Float16)b[0]; r[5] = (_Float16)b[1];
    r[6] = (_Float16)b[2]; r[7] = (_Float16)b[3];
    return r;
}

// non-temporal variant: single-use streaming fp32 inputs must not evict the
// LLC-resident intermediates (maskT/Kh/Vt) that attn re-reads 16x per bh.
__device__ inline h8 cvt_h8_nt(const float* __restrict__ p) {
    const f4* q = (const f4*)p;
    f4 a = __builtin_nontemporal_load(q);
    f4 b = __builtin_nontemporal_load(q + 1);
    h8 r;
    r[0] = (_Float16)a[0]; r[1] = (_Float16)a[1];
    r[2] = (_Float16)a[2]; r[3] = (_Float16)a[3];
    r[4] = (_Float16)b[0]; r[5] = (_Float16)b[1];
    r[6] = (_Float16)b[2]; r[7] = (_Float16)b[3];
    return r;
}

// ---------------------------------------------------------------------------
// maskT[j][i] (f16, 0 or -inf), j in [0,HW), i in [0,N). LDS tile transpose.
// ---------------------------------------------------------------------------
__global__ __launch_bounds__(256)
void mask_kernel(const float* __restrict__ x_tilde, const float* __restrict__ x_hat,
                 _Float16* __restrict__ maskT)
{
    __shared__ _Float16 T[64][72];
    int t  = threadIdx.x;
    int jl = t & 63;
    int iw = t >> 6;               // 0..3
    int j0 = blockIdx.x * 64;
    int i0 = blockIdx.y * 64;

    float xt0 = x_tilde[(j0 + jl) * 2 + 0];
    float xt1 = x_tilde[(j0 + jl) * 2 + 1];

    for (int ii = iw; ii < 64; ii += 4) {
        size_t idx = ((size_t)(i0 + ii) * HWK + j0 + jl) * 2;
        // x_hat is a 32 MB single-use stream: keep it out of the caches
        float h0 = __builtin_nontemporal_load(x_hat + idx + 0);
        float h1 = __builtin_nontemporal_load(x_hat + idx + 1);
        float dx = xt0 - h0, dy = xt1 - h1;
        // forbid fma-contraction so the boundary matches the reference bit-for-bit
        float d2 = __fadd_rn(__fmul_rn(dx, dx), __fmul_rn(dy, dy));
        float dist = __fsqrt_rn(d2);
        T[ii][jl] = (dist < 0.1f) ? (_Float16)0.0f : (_Float16)(-__builtin_inff());
    }
    __syncthreads();
    int il = t & 63;
    for (int jj = iw; jj < 64; jj += 4) {
        // maskT is re-read by attn (heavily) -> normal cached store
        maskT[(size_t)(j0 + jj) * NQ + i0 + il] = T[il][jj];
    }
}

// ---------------------------------------------------------------------------
// Q/K projection: C = X[M,512] @ W[512,512]^T + b, scaled, stored f16 as
// out[((b*NH+h) << nlog2) + n][dk], with m = (b << nlog2) + n, col = h*64+dk.
// block = 256 thr (4 waves), block tile 128x128, wave tile 64x64.
// ---------------------------------------------------------------------------
__global__ __launch_bounds__(256)
void proj_qk(const float* __restrict__ X, const float* __restrict__ W,
             const float* __restrict__ bias, _Float16* __restrict__ out,
             int nlog2, float scale)
{
    int tid = threadIdx.x;
    int w = tid >> 6, lane = tid & 63, q = lane >> 4, c = lane & 15;
    int wr = blockIdx.x * 128 + (w >> 1) * 64;
    int wc = blockIdx.y * 128 + (w & 1) * 64;

    f4 acc[4][4];
    const f4 fz = {0.f, 0.f, 0.f, 0.f};
#pragma unroll
    for (int i = 0; i < 4; i++)
#pragma unroll
        for (int j = 0; j < 4; j++) acc[i][j] = fz;

    for (int k0 = 0; k0 < DM; k0 += 32) {
        h8 af[4], bf[4];
#pragma unroll
        for (int i = 0; i < 4; i++)
            af[i] = cvt_h8_nt(X + (size_t)(wr + i * 16 + c) * DM + k0 + q * 8);  // X single-use
#pragma unroll
        for (int j = 0; j < 4; j++)
            bf[j] = cvt_h8(W + (size_t)(wc + j * 16 + c) * DM + k0 + q * 8);     // W reused
#pragma unroll
        for (int i = 0; i < 4; i++)
#pragma unroll
            for (int j = 0; j < 4; j++)
                acc[i][j] = __builtin_amdgcn_mfma_f32_16x16x32_f16(af[i], bf[j], acc[i][j], 0, 0, 0);
    }

    int nmask = (1 << nlog2) - 1;
#pragma unroll
    for (int j = 0; j < 4; j++) {
        int ncol = wc + j * 16 + c;
        float bb = bias[ncol];
        int hh = ncol >> 6, dk = ncol & 63;
#pragma unroll
        for (int i = 0; i < 4; i++) {
#pragma unroll
            for (int r = 0; r < 4; r++) {
                int m = wr + i * 16 + q * 4 + r;
                int b = m >> nlog2, n = m & nmask;
                float v = (acc[i][j][r] + bb) * scale;
                // Qh/Kh are re-read by attn -> normal cached store
                out[((((size_t)(b * NH + hh)) << nlog2) + n) * DKH + dk] = (_Float16)v;
            }
        }
    }
}

// ---------------------------------------------------------------------------
// V projection, transposed output: Vt[b,h,dk,m] = sum_k Wv[f,k]*value[m,k] + bv[f]
// A = Wv (M=feature 512), B = value^T (N = flat hw 16384).
// ---------------------------------------------------------------------------
__global__ __launch_bounds__(256)
void proj_v(const float* __restrict__ V, const float* __restrict__ W,
            const float* __restrict__ bias, _Float16* __restrict__ out)
{
    int tid = threadIdx.x;
    int w = tid >> 6, lane = tid & 63, q = lane >> 4, c = lane & 15;
    int wr = blockIdx.x * 128 + (w >> 1) * 64;   // feature
    int wc = blockIdx.y * 128 + (w & 1) * 64;    // flat hw

    f4 acc[4][4];
    const f4 fz = {0.f, 0.f, 0.f, 0.f};
#pragma unroll
    for (int i = 0; i < 4; i++)
#pragma unroll
        for (int j = 0; j < 4; j++) acc[i][j] = fz;

    for (int k0 = 0; k0 < DM; k0 += 32) {
        h8 af[4], bf[4];
#pragma unroll
        for (int i = 0; i < 4; i++)
            af[i] = cvt_h8(W + (size_t)(wr + i * 16 + c) * DM + k0 + q * 8);     // W reused
#pragma unroll
        for (int j = 0; j < 4; j++)
            bf[j] = cvt_h8_nt(V + (size_t)(wc + j * 16 + c) * DM + k0 + q * 8);  // value single-use
#pragma unroll
        for (int i = 0; i < 4; i++)
#pragma unroll
            for (int j = 0; j < 4; j++)
                acc[i][j] = __builtin_amdgcn_mfma_f32_16x16x32_f16(af[i], bf[j], acc[i][j], 0, 0, 0);
    }

#pragma unroll
    for (int i = 0; i < 4; i++) {
#pragma unroll
        for (int r = 0; r < 4; r++) {
            int f = wr + i * 16 + q * 4 + r;     // feature row
            float bb = bias[f];
            int hh = f >> 6, dk = f & 63;
#pragma unroll
            for (int j = 0; j < 4; j++) {
                int col = wc + j * 16 + c;       // flat hw
                int b = col >> 12, hw = col & 4095;
                // Vt is re-read by attn -> normal cached store
                out[((size_t)(b * NH + hh) * DKH + dk) * HWK + hw] =
                    (_Float16)(acc[i][j][r] + bb);
            }
        }
    }
}

// ---------------------------------------------------------------------------
// out = ctx_h[4096,512] (f16) @ Wo^T + bo  -> fp32
// ---------------------------------------------------------------------------
__global__ __launch_bounds__(256)
void proj_o(const _Float16* __restrict__ C, const float* __restrict__ W,
            const float* __restrict__ bias, float* __restrict__ out)
{
    int tid = threadIdx.x;
    int w = tid >> 6, lane = tid & 63, q = lane >> 4, c = lane & 15;
    int wr = blockIdx.x * 128 + (w >> 1) * 64;
    int wc = blockIdx.y * 128 + (w & 1) * 64;

    f4 acc[4][4];
    const f4 fz = {0.f, 0.f, 0.f, 0.f};
#pragma unroll
    for (int i = 0; i < 4; i++)
#pragma unroll
        for (int j = 0; j < 4; j++) acc[i][j] = fz;

    for (int k0 = 0; k0 < DM; k0 += 32) {
        h8 af[4], bf[4];
#pragma unroll
        for (int i = 0; i < 4; i++)
            af[i] = __builtin_nontemporal_load((const h8*)(C + (size_t)(wr + i * 16 + c) * DM + k0 + q * 8));
#pragma unroll
        for (int j = 0; j < 4; j++)
            bf[j] = cvt_h8(W + (size_t)(wc + j * 16 + c) * DM + k0 + q * 8);
#pragma unroll
        for (int i = 0; i < 4; i++)
#pragma unroll
            for (int j = 0; j < 4; j++)
                acc[i][j] = __builtin_amdgcn_mfma_f32_16x16x32_f16(af[i], bf[j], acc[i][j], 0, 0, 0);
    }

#pragma unroll
    for (int j = 0; j < 4; j++) {
        int ncol = wc + j * 16 + c;
        float bb = bias[ncol];
#pragma unroll
        for (int i = 0; i < 4; i++) {
#pragma unroll
            for (int r = 0; r < 4; r++) {
                int m = wr + i * 16 + q * 4 + r;
                __builtin_nontemporal_store(acc[i][j][r] + bb, &out[(size_t)m * DM + ncol]);
            }
        }
    }
}

// ---------------------------------------------------------------------------
// Attention: one block per (b,h, 64 q-rows). Pass1: row sums of masked exp.
// Pass2: recompute scores, write attn = e/l (coalesced via LDS), PV-MFMA ctx.
// ---------------------------------------------------------------------------
__global__ __launch_bounds__(256)
void attn_kernel(const _Float16* __restrict__ Qh, const _Float16* __restrict__ Kh,
                 const _Float16* __restrict__ Vt, const _Float16* __restrict__ maskT,
                 float* __restrict__ attn_out, _Float16* __restrict__ ctx_h)
{
    __shared__ union SmU {
        _Float16 P[4][64][72];   // per-wave 64x64 e-tile (f16), padded rows (144B = 9*16B)
        float    C[64][68];      // ctx cross-wave reduction buffer
    } sm;
    __shared__ float red[4][64];
    __shared__ float invl[64];

    int tid = threadIdx.x;
    int w = tid >> 6, lane = tid & 63, q = lane >> 4, c = lane & 15;
    int bh = blockIdx.x >> 4;
    int n0 = (blockIdx.x & 15) * 64;
    int b = bh >> 3, h = bh & 7;

    const _Float16* Qb = Qh + ((size_t)bh * NQ + n0) * DKH;
    const _Float16* Kb = Kh + (size_t)bh * HWK * DKH;
    const _Float16* Vb = Vt + (size_t)bh * DKH * HWK;
    float* attn_b = attn_out + ((size_t)bh * NQ + n0) * HWK;

    // Q fragments: held for the whole kernel (A-layout, k-contiguous)
    h8 qa[4][2];
#pragma unroll
    for (int i = 0; i < 4; i++)
#pragma unroll
        for (int ks = 0; ks < 2; ks++)
            qa[i][ks] = *(const h8*)(Qb + (size_t)(i * 16 + c) * DKH + ks * 32 + q * 8);

    // ---- pass 1: row sums ----
    float lsum[4][4];
#pragma unroll
    for (int i = 0; i < 4; i++)
#pragma unroll
        for (int r = 0; r < 4; r++) lsum[i][r] = 0.f;

    for (int it = 0; it < 16; ++it) {
        int m0 = it * 256 + w * 64;
        h8 kb[4][2];
#pragma unroll
        for (int j = 0; j < 4; j++)
#pragma unroll
            for (int ks = 0; ks < 2; ks++)
                kb[j][ks] = *(const h8*)(Kb + (size_t)(m0 + j * 16 + c) * DKH + ks * 32 + q * 8);
#pragma unroll
        for (int i = 0; i < 4; i++) {
#pragma unroll
            for (int j = 0; j < 4; j++) {
                f4 acc = {0.f, 0.f, 0.f, 0.f};
                acc = __builtin_amdgcn_mfma_f32_16x16x32_f16(qa[i][0], kb[j][0], acc, 0, 0, 0);
                acc = __builtin_amdgcn_mfma_f32_16x16x32_f16(qa[i][1], kb[j][1], acc, 0, 0, 0);
                h4 mk = *(const h4*)(maskT + (size_t)(m0 + j * 16 + c) * NQ + n0 + i * 16 + q * 4);
#pragma unroll
                for (int r = 0; r < 4; r++)
                    lsum[i][r] += __expf(acc[r] + (float)mk[r]);
            }
        }
    }

    // reduce over the 16 column-lanes; rows are i*16 + q*4 + r
#pragma unroll
    for (int i = 0; i < 4; i++) {
#pragma unroll
        for (int r = 0; r < 4; r++) {
            float s = lsum[i][r];
            s += __shfl_xor(s, 1);
            s += __shfl_xor(s, 2);
            s += __shfl_xor(s, 4);
            s += __shfl_xor(s, 8);
            if (c == 0) red[w][i * 16 + q * 4 + r] = s;
        }
    }
    __syncthreads();
    if (tid < 64)
        invl[tid] = 1.0f / (red[0][tid] + red[1][tid] + red[2][tid] + red[3][tid]);
    __syncthreads();

    // ---- pass 2: attn write + PV ----
    f4 cacc[4][4];
    const f4 fz = {0.f, 0.f, 0.f, 0.f};
#pragma unroll
    for (int i = 0; i < 4; i++)
#pragma unroll
        for (int jd = 0; jd < 4; jd++) cacc[i][jd] = fz;

    for (int it = 0; it < 16; ++it) {
        int m0 = it * 256 + w * 64;
        h8 kb[4][2];
#pragma unroll
        for (int j = 0; j < 4; j++)
#pragma unroll
            for (int ks = 0; ks < 2; ks++)
                kb[j][ks] = *(const h8*)(Kb + (size_t)(m0 + j * 16 + c) * DKH + ks * 32 + q * 8);

#pragma unroll
        for (int i = 0; i < 4; i++) {
#pragma unroll
            for (int j = 0; j < 4; j++) {
                f4 acc = {0.f, 0.f, 0.f, 0.f};
                acc = __builtin_amdgcn_mfma_f32_16x16x32_f16(qa[i][0], kb[j][0], acc, 0, 0, 0);
                acc = __builtin_amdgcn_mfma_f32_16x16x32_f16(qa[i][1], kb[j][1], acc, 0, 0, 0);
                h4 mk = *(const h4*)(maskT + (size_t)(m0 + j * 16 + c) * NQ + n0 + i * 16 + q * 4);
#pragma unroll
                for (int r = 0; r < 4; r++) {
                    float e = __expf(acc[r] + (float)mk[r]);
                    sm.P[w][i * 16 + q * 4 + r][j * 16 + c] = (_Float16)e;
                }
            }
        }
        // PV: ctx += P(64n x 64m) @ V^T slice (64m x 64dk). Same-wave LDS, no barrier.
#pragma unroll
        for (int ks = 0; ks < 2; ks++) {
            h8 pa[4], vb[4];
#pragma unroll
            for (int i = 0; i < 4; i++)
                pa[i] = *(const h8*)&sm.P[w][i * 16 + c][ks * 32 + q * 8];
#pragma unroll
            for (int jd = 0; jd < 4; jd++)
                vb[jd] = *(const h8*)(Vb + (size_t)(jd * 16 + c) * HWK + m0 + ks * 32 + q * 8);
#pragma unroll
            for (int i = 0; i < 4; i++)
#pragma unroll
                for (int jd = 0; jd < 4; jd++)
                    cacc[i][jd] = __builtin_amdgcn_mfma_f32_16x16x32_f16(pa[i], vb[jd], cacc[i][jd], 0, 0, 0);
        }
        // coalesced attn store: 4 rows x 64 cols per instruction group.
        // NON-TEMPORAL: this 512 MB fp32 stream must not evict maskT/Kh/Vt
        // from L2/LLC (they are re-read 16x per bh slice).
#pragma unroll
        for (int r0 = 0; r0 < 64; r0 += 4) {
            int row = r0 + q;
            h4 pv = *(const h4*)&sm.P[w][row][c * 4];
            float il = invl[row];
            f4 o;
            o[0] = (float)pv[0] * il;
            o[1] = (float)pv[1] * il;
            o[2] = (float)pv[2] * il;
            o[3] = (float)pv[3] * il;
            __builtin_nontemporal_store(o, (f4*)(attn_b + (size_t)row * HWK + m0 + c * 4));
        }
    }

    // ---- cross-wave ctx reduction, normalize, store f16 [b, n, h*64+dk] ----
    __syncthreads();
    for (int idx = tid; idx < 64 * 68; idx += 256)
        (&sm.C[0][0])[idx] = 0.f;
    __syncthreads();
#pragma unroll
    for (int i = 0; i < 4; i++)
#pragma unroll
        for (int jd = 0; jd < 4; jd++)
#pragma unroll
            for (int r = 0; r < 4; r++)
                atomicAdd(&sm.C[i * 16 + q * 4 + r][jd * 16 + c], cacc[i][jd][r]);
    __syncthreads();

    _Float16* ctx_b = ctx_h + ((size_t)b * NQ + n0) * DM + h * DKH;
    for (int r0 = 0; r0 < 64; r0 += 4) {
        int row = r0 + w;
        int col = tid & 63;
        float v = sm.C[row][col] * invl[row];
        ctx_b[(size_t)row * DM + col] = (_Float16)v;   // re-read by proj_o -> cached
    }
}

// ---------------------------------------------------------------------------
extern "C" void kernel_launch(void* const* d_in, const int* in_sizes, int n_in,
                              void* d_out, int out_size, void* d_ws, size_t ws_size,
                              hipStream_t stream)
{
    const float* query   = (const float*)d_in[0];
    const float* key     = (const float*)d_in[1];
    const float* value   = (const float*)d_in[2];
    const float* x_tilde = (const float*)d_in[3];
    const float* x_hat   = (const float*)d_in[4];
    const float* Wq = (const float*)d_in[5];
    const float* bq = (const float*)d_in[6];
    const float* Wk = (const float*)d_in[7];
    const float* bk = (const float*)d_in[8];
    const float* Wv = (const float*)d_in[9];
    const float* bv = (const float*)d_in[10];
    const float* Wo = (const float*)d_in[11];
    const float* bo = (const float*)d_in[12];

    char* ws = (char*)d_ws;
    _Float16* Qh    = (_Float16*)(ws);                       //  4 MB [B,H,N,64]
    _Float16* Kh    = (_Float16*)(ws + ((size_t)4  << 20));  // 16 MB [B,H,HW,64]
    _Float16* Vt    = (_Float16*)(ws + ((size_t)20 << 20));  // 16 MB [B,H,64,HW]
    _Float16* ctxh  = (_Float16*)(ws + ((size_t)36 << 20));  //  4 MB [B,N,512]
    _Float16* maskT = (_Float16*)(ws + ((size_t)40 << 20));  //  8 MB [HW,N]

    float* out  = (float*)d_out;
    float* attn = out + (size_t)4 * NQ * DM;   // out is [4,1024,512] then attn

    mask_kernel<<<dim3(HWK / 64, NQ / 64), 256, 0, stream>>>(x_tilde, x_hat, maskT);
    proj_qk<<<dim3(4 * NQ / 128, DM / 128), 256, 0, stream>>>(query, Wq, bq, Qh, 10, 0.125f);
    proj_qk<<<dim3(4 * HWK / 128, DM / 128), 256, 0, stream>>>(key, Wk, bk, Kh, 12, 1.0f);
    proj_v<<<dim3(DM / 128, 4 * HWK / 128), 256, 0, stream>>>(value, Wv, bv, Vt);
    attn_kernel<<<32 * (NQ / 64), 256, 0, stream>>>(Qh, Kh, Vt, maskT, attn, ctxh);
    proj_o<<<dim3(4 * NQ / 128, DM / 128), 256, 0, stream>>>(ctxh, Wo, bo, out);
}

// Round 2
// 953.083 us; speedup vs baseline: 1.0833x; 1.0786x over previous
//
#include <hip/hip_runtime.h>
#include <math.h>

typedef _Float16 h8 __attribute__((ext_vector_type(8)));
typedef _Float16 h4 __attribute__((ext_vector_type(4)));
typedef float    f4 __attribute__((ext_vector_type(4)));

#define NQ    1024
#define HWK   4096
#define DM    512
#define NH    8
#define DKH   64

// ---------------------------------------------------------------------------
// bulk fp32 -> f16 convert (RNE, identical to the (_Float16) casts previously
// done inline in the GEMM inner loops). NT loads: fp32 source is single-use.
// n8 = element count / 8.
// ---------------------------------------------------------------------------
__global__ __launch_bounds__(256)
void cvt_f16_kernel(const float* __restrict__ in, _Float16* __restrict__ out, int n8)
{
    int i = blockIdx.x * blockDim.x + threadIdx.x;
    if (i >= n8) return;
    const f4* q = (const f4*)(in + (size_t)i * 8);
    f4 a = __builtin_nontemporal_load(q);
    f4 b = __builtin_nontemporal_load(q + 1);
    h8 r;
    r[0] = (_Float16)a[0]; r[1] = (_Float16)a[1];
    r[2] = (_Float16)a[2]; r[3] = (_Float16)a[3];
    r[4] = (_Float16)b[0]; r[5] = (_Float16)b[1];
    r[6] = (_Float16)b[2]; r[7] = (_Float16)b[3];
    *(h8*)(out + (size_t)i * 8) = r;
}

// ---------------------------------------------------------------------------
// maskT[j][i] (f16, 0 or -inf), j in [0,HW), i in [0,N). LDS tile transpose.
// ---------------------------------------------------------------------------
__global__ __launch_bounds__(256)
void mask_kernel(const float* __restrict__ x_tilde, const float* __restrict__ x_hat,
                 _Float16* __restrict__ maskT)
{
    __shared__ _Float16 T[64][72];
    int t  = threadIdx.x;
    int jl = t & 63;
    int iw = t >> 6;               // 0..3
    int j0 = blockIdx.x * 64;
    int i0 = blockIdx.y * 64;

    float xt0 = x_tilde[(j0 + jl) * 2 + 0];
    float xt1 = x_tilde[(j0 + jl) * 2 + 1];

    for (int ii = iw; ii < 64; ii += 4) {
        size_t idx = ((size_t)(i0 + ii) * HWK + j0 + jl) * 2;
        float h0 = __builtin_nontemporal_load(x_hat + idx + 0);
        float h1 = __builtin_nontemporal_load(x_hat + idx + 1);
        float dx = xt0 - h0, dy = xt1 - h1;
        // forbid fma-contraction so the boundary matches the reference bit-for-bit
        float d2 = __fadd_rn(__fmul_rn(dx, dx), __fmul_rn(dy, dy));
        float dist = __fsqrt_rn(d2);
        T[ii][jl] = (dist < 0.1f) ? (_Float16)0.0f : (_Float16)(-__builtin_inff());
    }
    __syncthreads();
    int il = t & 63;
    for (int jj = iw; jj < 64; jj += 4) {
        maskT[(size_t)(j0 + jj) * NQ + i0 + il] = T[il][jj];
    }
}

// ---------------------------------------------------------------------------
// Q/K projection, all-f16 inputs: C = X[M,512] @ W[512,512]^T + b, scaled,
// stored f16 as out[((b*NH+h) << nlog2) + n][dk].
// block = 256 thr (4 waves), block tile 128x128, wave tile 64x64.
// Inner loop is pure h8 loads + MFMA (no cvt) -> MFMA-bound.
// ---------------------------------------------------------------------------
__global__ __launch_bounds__(256)
void proj_qk(const _Float16* __restrict__ X, const _Float16* __restrict__ W,
             const float* __restrict__ bias, _Float16* __restrict__ out,
             int nlog2, float scale)
{
    int tid = threadIdx.x;
    int w = tid >> 6, lane = tid & 63, q = lane >> 4, c = lane & 15;
    int wr = blockIdx.x * 128 + (w >> 1) * 64;
    int wc = blockIdx.y * 128 + (w & 1) * 64;

    f4 acc[4][4];
    const f4 fz = {0.f, 0.f, 0.f, 0.f};
#pragma unroll
    for (int i = 0; i < 4; i++)
#pragma unroll
        for (int j = 0; j < 4; j++) acc[i][j] = fz;

    for (int k0 = 0; k0 < DM; k0 += 32) {
        h8 af[4], bf[4];
#pragma unroll
        for (int i = 0; i < 4; i++)
            af[i] = *(const h8*)(X + (size_t)(wr + i * 16 + c) * DM + k0 + q * 8);
#pragma unroll
        for (int j = 0; j < 4; j++)
            bf[j] = *(const h8*)(W + (size_t)(wc + j * 16 + c) * DM + k0 + q * 8);
#pragma unroll
        for (int i = 0; i < 4; i++)
#pragma unroll
            for (int j = 0; j < 4; j++)
                acc[i][j] = __builtin_amdgcn_mfma_f32_16x16x32_f16(af[i], bf[j], acc[i][j], 0, 0, 0);
    }

    int nmask = (1 << nlog2) - 1;
#pragma unroll
    for (int j = 0; j < 4; j++) {
        int ncol = wc + j * 16 + c;
        float bb = bias[ncol];
        int hh = ncol >> 6, dk = ncol & 63;
#pragma unroll
        for (int i = 0; i < 4; i++) {
#pragma unroll
            for (int r = 0; r < 4; r++) {
                int m = wr + i * 16 + q * 4 + r;
                int b = m >> nlog2, n = m & nmask;
                float v = (acc[i][j][r] + bb) * scale;
                out[((((size_t)(b * NH + hh)) << nlog2) + n) * DKH + dk] = (_Float16)v;
            }
        }
    }
}

// ---------------------------------------------------------------------------
// V projection, all-f16, transposed output:
// Vt[b,h,dk,m] = sum_k Wv[f,k]*value[m,k] + bv[f]
// ---------------------------------------------------------------------------
__global__ __launch_bounds__(256)
void proj_v(const _Float16* __restrict__ V, const _Float16* __restrict__ W,
            const float* __restrict__ bias, _Float16* __restrict__ out)
{
    int tid = threadIdx.x;
    int w = tid >> 6, lane = tid & 63, q = lane >> 4, c = lane & 15;
    int wr = blockIdx.x * 128 + (w >> 1) * 64;   // feature
    int wc = blockIdx.y * 128 + (w & 1) * 64;    // flat hw

    f4 acc[4][4];
    const f4 fz = {0.f, 0.f, 0.f, 0.f};
#pragma unroll
    for (int i = 0; i < 4; i++)
#pragma unroll
        for (int j = 0; j < 4; j++) acc[i][j] = fz;

    for (int k0 = 0; k0 < DM; k0 += 32) {
        h8 af[4], bf[4];
#pragma unroll
        for (int i = 0; i < 4; i++)
            af[i] = *(const h8*)(W + (size_t)(wr + i * 16 + c) * DM + k0 + q * 8);
#pragma unroll
        for (int j = 0; j < 4; j++)
            bf[j] = *(const h8*)(V + (size_t)(wc + j * 16 + c) * DM + k0 + q * 8);
#pragma unroll
        for (int i = 0; i < 4; i++)
#pragma unroll
            for (int j = 0; j < 4; j++)
                acc[i][j] = __builtin_amdgcn_mfma_f32_16x16x32_f16(af[i], bf[j], acc[i][j], 0, 0, 0);
    }

#pragma unroll
    for (int i = 0; i < 4; i++) {
#pragma unroll
        for (int r = 0; r < 4; r++) {
            int f = wr + i * 16 + q * 4 + r;     // feature row
            float bb = bias[f];
            int hh = f >> 6, dk = f & 63;
#pragma unroll
            for (int j = 0; j < 4; j++) {
                int col = wc + j * 16 + c;       // flat hw
                int b = col >> 12, hw = col & 4095;
                out[((size_t)(b * NH + hh) * DKH + dk) * HWK + hw] =
                    (_Float16)(acc[i][j][r] + bb);
            }
        }
    }
}

// ---------------------------------------------------------------------------
// out = ctx_h[4096,512] (f16) @ Wo^T (f16) + bo  -> fp32
// ---------------------------------------------------------------------------
__global__ __launch_bounds__(256)
void proj_o(const _Float16* __restrict__ C, const _Float16* __restrict__ W,
            const float* __restrict__ bias, float* __restrict__ out)
{
    int tid = threadIdx.x;
    int w = tid >> 6, lane = tid & 63, q = lane >> 4, c = lane & 15;
    int wr = blockIdx.x * 128 + (w >> 1) * 64;
    int wc = blockIdx.y * 128 + (w & 1) * 64;

    f4 acc[4][4];
    const f4 fz = {0.f, 0.f, 0.f, 0.f};
#pragma unroll
    for (int i = 0; i < 4; i++)
#pragma unroll
        for (int j = 0; j < 4; j++) acc[i][j] = fz;

    for (int k0 = 0; k0 < DM; k0 += 32) {
        h8 af[4], bf[4];
#pragma unroll
        for (int i = 0; i < 4; i++)
            af[i] = *(const h8*)(C + (size_t)(wr + i * 16 + c) * DM + k0 + q * 8);
#pragma unroll
        for (int j = 0; j < 4; j++)
            bf[j] = *(const h8*)(W + (size_t)(wc + j * 16 + c) * DM + k0 + q * 8);
#pragma unroll
        for (int i = 0; i < 4; i++)
#pragma unroll
            for (int j = 0; j < 4; j++)
                acc[i][j] = __builtin_amdgcn_mfma_f32_16x16x32_f16(af[i], bf[j], acc[i][j], 0, 0, 0);
    }

#pragma unroll
    for (int j = 0; j < 4; j++) {
        int ncol = wc + j * 16 + c;
        float bb = bias[ncol];
#pragma unroll
        for (int i = 0; i < 4; i++) {
#pragma unroll
            for (int r = 0; r < 4; r++) {
                int m = wr + i * 16 + q * 4 + r;
                __builtin_nontemporal_store(acc[i][j][r] + bb, &out[(size_t)m * DM + ncol]);
            }
        }
    }
}

// ---------------------------------------------------------------------------
// Attention: one block per (b,h, 64 q-rows). Pass1: row sums of masked exp.
// Pass2: recompute scores, write attn = e/l (coalesced via LDS), PV-MFMA ctx.
// ---------------------------------------------------------------------------
__global__ __launch_bounds__(256)
void attn_kernel(const _Float16* __restrict__ Qh, const _Float16* __restrict__ Kh,
                 const _Float16* __restrict__ Vt, const _Float16* __restrict__ maskT,
                 float* __restrict__ attn_out, _Float16* __restrict__ ctx_h)
{
    __shared__ union SmU {
        _Float16 P[4][64][72];   // per-wave 64x64 e-tile (f16), padded rows (144B = 9*16B)
        float    C[64][68];      // ctx cross-wave reduction buffer
    } sm;
    __shared__ float red[4][64];
    __shared__ float invl[64];

    int tid = threadIdx.x;
    int w = tid >> 6, lane = tid & 63, q = lane >> 4, c = lane & 15;
    int bh = blockIdx.x >> 4;
    int n0 = (blockIdx.x & 15) * 64;
    int b = bh >> 3, h = bh & 7;

    const _Float16* Qb = Qh + ((size_t)bh * NQ + n0) * DKH;
    const _Float16* Kb = Kh + (size_t)bh * HWK * DKH;
    const _Float16* Vb = Vt + (size_t)bh * DKH * HWK;
    float* attn_b = attn_out + ((size_t)bh * NQ + n0) * HWK;

    // Q fragments: held for the whole kernel (A-layout, k-contiguous)
    h8 qa[4][2];
#pragma unroll
    for (int i = 0; i < 4; i++)
#pragma unroll
        for (int ks = 0; ks < 2; ks++)
            qa[i][ks] = *(const h8*)(Qb + (size_t)(i * 16 + c) * DKH + ks * 32 + q * 8);

    // ---- pass 1: row sums ----
    float lsum[4][4];
#pragma unroll
    for (int i = 0; i < 4; i++)
#pragma unroll
        for (int r = 0; r < 4; r++) lsum[i][r] = 0.f;

    for (int it = 0; it < 16; ++it) {
        int m0 = it * 256 + w * 64;
        h8 kb[4][2];
#pragma unroll
        for (int j = 0; j < 4; j++)
#pragma unroll
            for (int ks = 0; ks < 2; ks++)
                kb[j][ks] = *(const h8*)(Kb + (size_t)(m0 + j * 16 + c) * DKH + ks * 32 + q * 8);
#pragma unroll
        for (int i = 0; i < 4; i++) {
#pragma unroll
            for (int j = 0; j < 4; j++) {
                f4 acc = {0.f, 0.f, 0.f, 0.f};
                acc = __builtin_amdgcn_mfma_f32_16x16x32_f16(qa[i][0], kb[j][0], acc, 0, 0, 0);
                acc = __builtin_amdgcn_mfma_f32_16x16x32_f16(qa[i][1], kb[j][1], acc, 0, 0, 0);
                h4 mk = *(const h4*)(maskT + (size_t)(m0 + j * 16 + c) * NQ + n0 + i * 16 + q * 4);
#pragma unroll
                for (int r = 0; r < 4; r++)
                    lsum[i][r] += __expf(acc[r] + (float)mk[r]);
            }
        }
    }

    // reduce over the 16 column-lanes; rows are i*16 + q*4 + r
#pragma unroll
    for (int i = 0; i < 4; i++) {
#pragma unroll
        for (int r = 0; r < 4; r++) {
            float s = lsum[i][r];
            s += __shfl_xor(s, 1);
            s += __shfl_xor(s, 2);
            s += __shfl_xor(s, 4);
            s += __shfl_xor(s, 8);
            if (c == 0) red[w][i * 16 + q * 4 + r] = s;
        }
    }
    __syncthreads();
    if (tid < 64)
        invl[tid] = 1.0f / (red[0][tid] + red[1][tid] + red[2][tid] + red[3][tid]);
    __syncthreads();

    // ---- pass 2: attn write + PV ----
    f4 cacc[4][4];
    const f4 fz = {0.f, 0.f, 0.f, 0.f};
#pragma unroll
    for (int i = 0; i < 4; i++)
#pragma unroll
        for (int jd = 0; jd < 4; jd++) cacc[i][jd] = fz;

    for (int it = 0; it < 16; ++it) {
        int m0 = it * 256 + w * 64;
        h8 kb[4][2];
#pragma unroll
        for (int j = 0; j < 4; j++)
#pragma unroll
            for (int ks = 0; ks < 2; ks++)
                kb[j][ks] = *(const h8*)(Kb + (size_t)(m0 + j * 16 + c) * DKH + ks * 32 + q * 8);

#pragma unroll
        for (int i = 0; i < 4; i++) {
#pragma unroll
            for (int j = 0; j < 4; j++) {
                f4 acc = {0.f, 0.f, 0.f, 0.f};
                acc = __builtin_amdgcn_mfma_f32_16x16x32_f16(qa[i][0], kb[j][0], acc, 0, 0, 0);
                acc = __builtin_amdgcn_mfma_f32_16x16x32_f16(qa[i][1], kb[j][1], acc, 0, 0, 0);
                h4 mk = *(const h4*)(maskT + (size_t)(m0 + j * 16 + c) * NQ + n0 + i * 16 + q * 4);
#pragma unroll
                for (int r = 0; r < 4; r++) {
                    float e = __expf(acc[r] + (float)mk[r]);
                    sm.P[w][i * 16 + q * 4 + r][j * 16 + c] = (_Float16)e;
                }
            }
        }
        // PV: ctx += P(64n x 64m) @ V^T slice (64m x 64dk). Same-wave LDS, no barrier.
#pragma unroll
        for (int ks = 0; ks < 2; ks++) {
            h8 pa[4], vb[4];
#pragma unroll
            for (int i = 0; i < 4; i++)
                pa[i] = *(const h8*)&sm.P[w][i * 16 + c][ks * 32 + q * 8];
#pragma unroll
            for (int jd = 0; jd < 4; jd++)
                vb[jd] = *(const h8*)(Vb + (size_t)(jd * 16 + c) * HWK + m0 + ks * 32 + q * 8);
#pragma unroll
            for (int i = 0; i < 4; i++)
#pragma unroll
                for (int jd = 0; jd < 4; jd++)
                    cacc[i][jd] = __builtin_amdgcn_mfma_f32_16x16x32_f16(pa[i], vb[jd], cacc[i][jd], 0, 0, 0);
        }
        // coalesced attn store: 4 rows x 64 cols per instruction group (NT).
#pragma unroll
        for (int r0 = 0; r0 < 64; r0 += 4) {
            int row = r0 + q;
            h4 pv = *(const h4*)&sm.P[w][row][c * 4];
            float il = invl[row];
            f4 o;
            o[0] = (float)pv[0] * il;
            o[1] = (float)pv[1] * il;
            o[2] = (float)pv[2] * il;
            o[3] = (float)pv[3] * il;
            __builtin_nontemporal_store(o, (f4*)(attn_b + (size_t)row * HWK + m0 + c * 4));
        }
    }

    // ---- cross-wave ctx reduction, normalize, store f16 [b, n, h*64+dk] ----
    __syncthreads();
    for (int idx = tid; idx < 64 * 68; idx += 256)
        (&sm.C[0][0])[idx] = 0.f;
    __syncthreads();
#pragma unroll
    for (int i = 0; i < 4; i++)
#pragma unroll
        for (int jd = 0; jd < 4; jd++)
#pragma unroll
            for (int r = 0; r < 4; r++)
                atomicAdd(&sm.C[i * 16 + q * 4 + r][jd * 16 + c], cacc[i][jd][r]);
    __syncthreads();

    _Float16* ctx_b = ctx_h + ((size_t)b * NQ + n0) * DM + h * DKH;
    for (int r0 = 0; r0 < 64; r0 += 4) {
        int row = r0 + w;
        int col = tid & 63;
        float v = sm.C[row][col] * invl[row];
        ctx_b[(size_t)row * DM + col] = (_Float16)v;   // re-read by proj_o -> cached
    }
}

// ---------------------------------------------------------------------------
extern "C" void kernel_launch(void* const* d_in, const int* in_sizes, int n_in,
                              void* d_out, int out_size, void* d_ws, size_t ws_size,
                              hipStream_t stream)
{
    const float* query   = (const float*)d_in[0];
    const float* key     = (const float*)d_in[1];
    const float* value   = (const float*)d_in[2];
    const float* x_tilde = (const float*)d_in[3];
    const float* x_hat   = (const float*)d_in[4];
    const float* Wq = (const float*)d_in[5];
    const float* bq = (const float*)d_in[6];
    const float* Wk = (const float*)d_in[7];
    const float* bk = (const float*)d_in[8];
    const float* Wv = (const float*)d_in[9];
    const float* bv = (const float*)d_in[10];
    const float* Wo = (const float*)d_in[11];
    const float* bo = (const float*)d_in[12];

    char* ws = (char*)d_ws;
    _Float16* Qh    = (_Float16*)(ws);                       //  4 MB [B,H,N,64]
    _Float16* Kh    = (_Float16*)(ws + ((size_t)4  << 20));  // 16 MB [B,H,HW,64]
    _Float16* Vt    = (_Float16*)(ws + ((size_t)20 << 20));  // 16 MB [B,H,64,HW]
    _Float16* ctxh  = (_Float16*)(ws + ((size_t)36 << 20));  //  4 MB [B,N,512]
    _Float16* maskT = (_Float16*)(ws + ((size_t)40 << 20));  //  8 MB [HW,N]
    _Float16* Xq    = (_Float16*)(ws + ((size_t)48 << 20));  //  4 MB query f16
    _Float16* Xk    = (_Float16*)(ws + ((size_t)52 << 20));  // 16 MB key f16
    _Float16* Xv    = (_Float16*)(ws + ((size_t)68 << 20));  // 16 MB value f16
    _Float16* Wqh   = (_Float16*)(ws + ((size_t)84 << 20));  // 0.5 MB
    _Float16* Wkh   = (_Float16*)(ws + ((size_t)84 << 20) + (512 * 1024));
    _Float16* Wvh   = (_Float16*)(ws + ((size_t)84 << 20) + (1024 * 1024));
    _Float16* Woh   = (_Float16*)(ws + ((size_t)84 << 20) + (1536 * 1024));

    float* out  = (float*)d_out;
    float* attn = out + (size_t)4 * NQ * DM;   // out is [4,1024,512] then attn

    // one-time f16 conversion of GEMM inputs (RNE, bit-identical to old inline casts)
    const int NW8 = DM * DM / 8;  // 32768 per weight matrix
    cvt_f16_kernel<<<(4 * NQ * DM / 8 + 255) / 256, 256, 0, stream>>>(query, Xq, 4 * NQ * DM / 8);
    cvt_f16_kernel<<<(4 * HWK * DM / 8 + 255) / 256, 256, 0, stream>>>(key, Xk, 4 * HWK * DM / 8);
    cvt_f16_kernel<<<(4 * HWK * DM / 8 + 255) / 256, 256, 0, stream>>>(value, Xv, 4 * HWK * DM / 8);
    cvt_f16_kernel<<<(NW8 + 255) / 256, 256, 0, stream>>>(Wq, Wqh, NW8);
    cvt_f16_kernel<<<(NW8 + 255) / 256, 256, 0, stream>>>(Wk, Wkh, NW8);
    cvt_f16_kernel<<<(NW8 + 255) / 256, 256, 0, stream>>>(Wv, Wvh, NW8);
    cvt_f16_kernel<<<(NW8 + 255) / 256, 256, 0, stream>>>(Wo, Woh, NW8);

    mask_kernel<<<dim3(HWK / 64, NQ / 64), 256, 0, stream>>>(x_tilde, x_hat, maskT);
    proj_qk<<<dim3(4 * NQ / 128, DM / 128), 256, 0, stream>>>(Xq, Wqh, bq, Qh, 10, 0.125f);
    proj_qk<<<dim3(4 * HWK / 128, DM / 128), 256, 0, stream>>>(Xk, Wkh, bk, Kh, 12, 1.0f);
    proj_v<<<dim3(DM / 128, 4 * HWK / 128), 256, 0, stream>>>(Xv, Wvh, bv, Vt);
    attn_kernel<<<32 * (NQ / 64), 256, 0, stream>>>(Qh, Kh, Vt, maskT, attn, ctxh);
    proj_o<<<dim3(4 * NQ / 128, DM / 128), 256, 0, stream>>>(ctxh, Woh, bo, out);
}